// Round 7
// baseline (1155.444 us; speedup 1.0000x reference)
//
#include <hip/hip_runtime.h>
#include <math.h>

#define NPTS 4096
#define KNN  20
#define BLK  128   // 32 blocks per batch -> 256 blocks total (1 per CU)

__global__ __launch_bounds__(BLK) void gap_layer_kernel(
    const float* __restrict__ x,
    const float* __restrict__ w1,
    const float* __restrict__ g1, const float* __restrict__ be1,
    const float* __restrict__ mu1, const float* __restrict__ va1,
    const float* __restrict__ w2, const float* __restrict__ b2,
    const float* __restrict__ g2, const float* __restrict__ be2,
    const float* __restrict__ mu2, const float* __restrict__ va2,
    const float* __restrict__ w3, const float* __restrict__ b3,
    const float* __restrict__ g3, const float* __restrict__ be3,
    const float* __restrict__ mu3, const float* __restrict__ va3,
    float* __restrict__ out_ret,   // (B, N, 16) flat
    float* __restrict__ out_edge)  // (B, 16, N, KNN) flat
{
    __shared__ float sx[NPTS], sy[NPTS], sz[NPTS];
    __shared__ float sxx[NPTS];                 // fp32 xx: no-FMA (np ufunc path)
    __shared__ float fw1[16][3], fb1[16], fw2[16][3], fb2[16], fw3[16];
    __shared__ float fb3s;

    const int tid   = threadIdx.x;
    const int bpb   = NPTS / BLK;            // blocks per batch = 32
    const int b     = blockIdx.x / bpb;
    const int nbase = (blockIdx.x % bpb) * BLK;

    // ---- stage all points of this batch into LDS; precompute fp32 xx ----
    const float* xb = x + (size_t)b * 3 * NPTS;
    for (int m = tid; m < NPTS; m += BLK) {
        #pragma clang fp contract(off)
        const float a = xb[m];
        const float c = xb[NPTS + m];
        const float e = xb[2 * NPTS + m];
        sx[m] = a; sy[m] = c; sz[m] = e;
        // np: xx = sum(x*x,axis=1): rounded products, sequential adds, NO fma
        const float pa = a * a;
        const float pc = c * c;
        const float pe = e * e;
        const float s01 = pa + pc;
        sxx[m] = s01 + pe;
    }
    // ---- fold BN into conv weights (threads 0..15, one output channel each) ----
    if (tid < 16) {
        const int o = tid;
        float s1 = g1[o] * rsqrtf(va1[o] + 1e-5f);
        fb1[o] = -mu1[o] * s1 + be1[o];
        #pragma unroll
        for (int c = 0; c < 3; ++c) fw1[o][c] = w1[o * 3 + c] * s1;
        float s2 = g2[o] * rsqrtf(va2[o] + 1e-5f);
        fb2[o] = (b2[o] - mu2[o]) * s2 + be2[o];
        #pragma unroll
        for (int c = 0; c < 3; ++c) fw2[o][c] = w2[o * 3 + c] * s2;
        float s3 = g3[0] * rsqrtf(va3[0] + 1e-5f);
        fw3[o] = w3[o] * s3;
        if (o == 0) fb3s = (b3[0] - mu3[0]) * s3 + be3[0];
    }
    __syncthreads();

    const int n = nbase + tid;
    const float xnf = sx[n], ynf = sy[n], znf = sz[n];
    const float xxn = sxx[n];

    // ---- top-K by neg squared distance; np-matched fp32 key:
    //      inner = fma(z,zm, fma(y,ym, round(x*xm)))  [einsum AVX2 scalar tail]
    //      xx    = (x^2+y^2)+z^2 no-FMA               [multiply + add.reduce]
    //      v     = (2*inner - xx_m) - xx_n, per-op rounded (separate ufuncs)
    //      Ties: stable, lower index first (strict >). ----
    float bv[KNN];
    int   bi[KNN];
    #pragma unroll
    for (int j = 0; j < KNN; ++j) { bv[j] = -3.4e38f; bi[j] = 0; }

    for (int m = 0; m < NPTS; ++m) {
        float v;
        {
            #pragma clang fp contract(off)
            const float p0    = xnf * sx[m];
            const float f1    = __builtin_fmaf(ynf, sy[m], p0);
            const float inner = __builtin_fmaf(znf, sz[m], f1);
            const float two_i = 2.0f * inner;
            const float t     = two_i - sxx[m];
            v = t - xxn;
        }
        if (v > bv[KNN - 1]) {
            bool c[KNN];
            #pragma unroll
            for (int j = 0; j < KNN; ++j) c[j] = v > bv[j];
            #pragma unroll
            for (int j = KNN - 1; j >= 1; --j) {
                bv[j] = c[j] ? (c[j - 1] ? bv[j - 1] : v) : bv[j];
                bi[j] = c[j] ? (c[j - 1] ? bi[j - 1] : m) : bi[j];
            }
            if (c[0]) { bv[0] = v; bi[0] = m; }
        }
    }

    // ---- edge diffs (fp32, single op each) ----
    float d0[KNN], d1[KNN], d2[KNN];
    #pragma unroll
    for (int k = 0; k < KNN; ++k) {
        const int m = bi[k];
        d0[k] = xnf - sx[m];
        d1[k] = ynf - sy[m];
        d2[k] = znf - sz[m];
    }

    // ---- attention logits + edge_feature output ----
    float sacc[KNN], nacc[KNN];
    #pragma unroll
    for (int k = 0; k < KNN; ++k) { sacc[k] = 0.f; nacc[k] = 0.f; }

    const float fb3 = fb3s;
    for (int o = 0; o < 16; ++o) {
        const float a0 = fw1[o][0], a1 = fw1[o][1], a2 = fw1[o][2], ab = fb1[o];
        const float e0 = fw2[o][0], e1 = fw2[o][1], e2 = fw2[o][2], eb = fb2[o];
        const float w3o = fw3[o];
        const size_t ebase = (((size_t)b * 16 + o) * NPTS + n) * KNN;
        #pragma unroll
        for (int k = 0; k < KNN; ++k) {
            float f1 = fmaf(d2[k], a2, fmaf(d1[k], a1, fmaf(d0[k], a0, ab)));
            f1 = fmaxf(f1, 0.f);
            sacc[k] = fmaf(f1, w3o, sacc[k]);
            float ee = fmaf(d2[k], e2, fmaf(d1[k], e1, fmaf(d0[k], e0, eb)));
            ee = fmaxf(ee, 0.f);
            nacc[k] = fmaf(ee, w3o, nacc[k]);
            out_edge[ebase + k] = ee;
        }
    }

    // ---- leaky_relu + softmax over k ----
    float att[KNN];
    float mx = -3.4e38f;
    #pragma unroll
    for (int k = 0; k < KNN; ++k) {
        float l = fmaxf(sacc[k] + fb3, 0.f) + fmaxf(nacc[k] + fb3, 0.f);
        l = (l >= 0.f) ? l : 0.01f * l;   // leaky_relu
        att[k] = l;
        mx = fmaxf(mx, l);
    }
    float sum = 0.f;
    #pragma unroll
    for (int k = 0; k < KNN; ++k) { att[k] = expf(att[k] - mx); sum += att[k]; }
    const float inv = 1.f / sum;
    #pragma unroll
    for (int k = 0; k < KNN; ++k) att[k] *= inv;

    // ---- weighted edge sum (recompute edge), elu, write ret ----
    const size_t rbase = ((size_t)b * NPTS + n) * 16;
    for (int o = 0; o < 16; ++o) {
        const float e0 = fw2[o][0], e1 = fw2[o][1], e2 = fw2[o][2], eb = fb2[o];
        float val = 0.f;
        #pragma unroll
        for (int k = 0; k < KNN; ++k) {
            float ee = fmaf(d2[k], e2, fmaf(d1[k], e1, fmaf(d0[k], e0, eb)));
            ee = fmaxf(ee, 0.f);
            val = fmaf(att[k], ee, val);
        }
        const float r = (val > 0.f) ? val : expm1f(val);
        out_ret[rbase + o] = r;
    }
}

extern "C" void kernel_launch(void* const* d_in, const int* in_sizes, int n_in,
                              void* d_out, int out_size, void* d_ws, size_t ws_size,
                              hipStream_t stream) {
    const float* x   = (const float*)d_in[0];
    const float* w1  = (const float*)d_in[1];
    const float* g1  = (const float*)d_in[2];
    const float* be1 = (const float*)d_in[3];
    const float* mu1 = (const float*)d_in[4];
    const float* va1 = (const float*)d_in[5];
    const float* w2  = (const float*)d_in[6];
    const float* b2  = (const float*)d_in[7];
    const float* g2  = (const float*)d_in[8];
    const float* be2 = (const float*)d_in[9];
    const float* mu2 = (const float*)d_in[10];
    const float* va2 = (const float*)d_in[11];
    const float* w3  = (const float*)d_in[12];
    const float* b3  = (const float*)d_in[13];
    const float* g3  = (const float*)d_in[14];
    const float* be3 = (const float*)d_in[15];
    const float* mu3 = (const float*)d_in[16];
    const float* va3 = (const float*)d_in[17];

    const int B = in_sizes[0] / (3 * NPTS);   // = 8
    float* out_ret  = (float*)d_out;                          // B*N*16
    float* out_edge = out_ret + (size_t)B * NPTS * 16;        // B*16*N*K

    const int grid = B * (NPTS / BLK);
    gap_layer_kernel<<<grid, BLK, 0, stream>>>(
        x, w1, g1, be1, mu1, va1, w2, b2, g2, be2, mu2, va2,
        w3, b3, g3, be3, mu3, va3, out_ret, out_edge);
}

// Round 8
// 535.226 us; speedup vs baseline: 2.1588x; 2.1588x over previous
//
#include <hip/hip_runtime.h>
#include <math.h>

#define NPTS  4096
#define KNN   20
#define BLK   256
#define SPLIT 4
#define CHUNK (NPTS / SPLIT)   // 1024 candidates per sub-scan
#define PPB   (BLK / SPLIT)    // 64 points per block
#define NEGBIG -3.4e38f

// Merge scratch: one row of 21 float2 (168B, padded to break power-of-2 bank
// stride) per (point, chunk). 64*4*21*8 = 43008 B LDS.
#define ROWSTRIDE 21

__global__ __launch_bounds__(BLK, 4) void gap_layer_kernel(
    const float* __restrict__ x,
    const float* __restrict__ w1,
    const float* __restrict__ g1, const float* __restrict__ be1,
    const float* __restrict__ mu1, const float* __restrict__ va1,
    const float* __restrict__ w2, const float* __restrict__ b2,
    const float* __restrict__ g2, const float* __restrict__ be2,
    const float* __restrict__ mu2, const float* __restrict__ va2,
    const float* __restrict__ w3, const float* __restrict__ b3,
    const float* __restrict__ g3, const float* __restrict__ be3,
    const float* __restrict__ mu3, const float* __restrict__ va3,
    float* __restrict__ out_ret,   // (B, N, 16) flat
    float* __restrict__ out_edge)  // (B, 16, N, KNN) flat
{
    __shared__ float2 smrg[PPB * SPLIT * ROWSTRIDE];
    __shared__ float4 wA[16], wE[16];
    __shared__ float  w3s[16];
    __shared__ float  fb3s;

    const int tid = threadIdx.x;
    const int p   = tid >> 2;      // local point 0..63
    const int c   = tid & 3;       // chunk id 0..3
    const int b     = blockIdx.x >> 6;            // 8 batches * 64 blocks
    const int nbase = (blockIdx.x & 63) * PPB;
    const int n     = nbase + p;

    // ---- fold BN into conv weights (lanes 0..15 of wave 0) ----
    if (tid < 16) {
        const int o = tid;
        float s1 = g1[o] * rsqrtf(va1[o] + 1e-5f);
        float fb1o = -mu1[o] * s1 + be1[o];
        wA[o] = make_float4(w1[o*3+0]*s1, w1[o*3+1]*s1, w1[o*3+2]*s1, fb1o);
        float s2 = g2[o] * rsqrtf(va2[o] + 1e-5f);
        float fb2o = (b2[o] - mu2[o]) * s2 + be2[o];
        wE[o] = make_float4(w2[o*3+0]*s2, w2[o*3+1]*s2, w2[o*3+2]*s2, fb2o);
        float s3 = g3[0] * rsqrtf(va3[0] + 1e-5f);
        w3s[o] = w3[o] * s3;
        if (o == 0) fb3s = (b3[0] - mu3[0]) * s3 + be3[0];
    }

    const float* xg = x + (size_t)b * 3 * NPTS;

    // ---- own point coords + xx (frozen np rounding: no-FMA) ----
    const float xnf = xg[n], ynf = xg[NPTS + n], znf = xg[2 * NPTS + n];
    float xxn;
    {
        #pragma clang fp contract(off)
        const float pa = xnf * xnf;
        const float pc = ynf * ynf;
        const float pe = znf * znf;
        const float s01 = pa + pc;
        xxn = s01 + pe;
    }

    // ---- sub-scan: chunk c covers m = 4t + c, t in [0,1024) ----
    // key (frozen, bit-matches np): inner = fma(z,zm, fma(y,ym, x*xm));
    // xxm no-FMA; v = (2*inner - xxm) - xxn per-op rounded. Stable strict >.
    float bv[KNN];
    int   bi[KNN];
    #pragma unroll
    for (int j = 0; j < KNN; ++j) { bv[j] = NEGBIG; bi[j] = 0; }

    #pragma unroll 2
    for (int t = 0; t < CHUNK; ++t) {
        const int m = (t << 2) | c;
        const float am = xg[m];
        const float cm = xg[NPTS + m];
        const float em = xg[2 * NPTS + m];
        float v;
        {
            #pragma clang fp contract(off)
            const float qa = am * am;
            const float qc = cm * cm;
            const float qe = em * em;
            const float s01 = qa + qc;
            const float xxm = s01 + qe;
            const float p0    = xnf * am;
            const float f1    = __builtin_fmaf(ynf, cm, p0);
            const float inner = __builtin_fmaf(znf, em, f1);
            const float two_i = 2.0f * inner;
            const float tt    = two_i - xxm;
            v = tt - xxn;
        }
        if (v > bv[KNN - 1]) {
            bool cc[KNN];
            #pragma unroll
            for (int j = 0; j < KNN; ++j) cc[j] = v > bv[j];
            #pragma unroll
            for (int j = KNN - 1; j >= 1; --j) {
                bv[j] = cc[j] ? (cc[j - 1] ? bv[j - 1] : v) : bv[j];
                bi[j] = cc[j] ? (cc[j - 1] ? bi[j - 1] : m) : bi[j];
            }
            if (cc[0]) { bv[0] = v; bi[0] = m; }
        }
    }

    // ---- publish sorted sub-lists to LDS ----
    {
        float2* row = &smrg[tid * ROWSTRIDE];   // (p*4+c) == tid
        #pragma unroll
        for (int j = 0; j < KNN; ++j)
            row[j] = make_float2(bv[j], __int_as_float(bi[j]));
    }
    __syncthreads();

    // ---- 4-way merge (all 4 lanes of a point walk identically; lane c
    //      records ranks r with r%4==c). Comparator: v desc, idx asc. ----
    const float2* base = &smrg[(p << 2) * ROWSTRIDE];
    float2 h;
    h = base[0];                 float hv0 = h.x; int hi0 = __float_as_int(h.y);
    h = base[ROWSTRIDE];         float hv1 = h.x; int hi1 = __float_as_int(h.y);
    h = base[2 * ROWSTRIDE];     float hv2 = h.x; int hi2 = __float_as_int(h.y);
    h = base[3 * ROWSTRIDE];     float hv3 = h.x; int hi3 = __float_as_int(h.y);
    int q0 = 1, q1 = 1, q2 = 1, q3 = 1;
    int mi0 = 0, mi1 = 0, mi2 = 0, mi3 = 0, mi4 = 0;

    #pragma unroll
    for (int r = 0; r < KNN; ++r) {
        const bool b01 = (hv1 > hv0) || (hv1 == hv0 && hi1 < hi0);
        const float av = b01 ? hv1 : hv0;
        const int   ai = b01 ? hi1 : hi0;
        const int   aw = b01 ? 1 : 0;
        const bool b23 = (hv3 > hv2) || (hv3 == hv2 && hi3 < hi2);
        const float bvv = b23 ? hv3 : hv2;
        const int   bii = b23 ? hi3 : hi2;
        const int   bw  = b23 ? 3 : 2;
        const bool bab = (bvv > av) || (bvv == av && bii < ai);
        const int wi = bab ? bii : ai;
        const int ww = bab ? bw : aw;

        if ((r & 3) == c) {
            const int j = r >> 2;
            mi0 = (j == 0) ? wi : mi0;
            mi1 = (j == 1) ? wi : mi1;
            mi2 = (j == 2) ? wi : mi2;
            mi3 = (j == 3) ? wi : mi3;
            mi4 = (j == 4) ? wi : mi4;
        }

        const int qw = (ww == 0) ? q0 : (ww == 1) ? q1 : (ww == 2) ? q2 : q3;
        const int rd = (qw < KNN - 1) ? qw : (KNN - 1);
        const float2 nh = base[ww * ROWSTRIDE + rd];
        const float nv = (qw < KNN) ? nh.x : NEGBIG;
        const int   ni = __float_as_int(nh.y);
        q0 += (ww == 0); q1 += (ww == 1); q2 += (ww == 2); q3 += (ww == 3);
        hv0 = (ww == 0) ? nv : hv0;  hi0 = (ww == 0) ? ni : hi0;
        hv1 = (ww == 1) ? nv : hv1;  hi1 = (ww == 1) ? ni : hi1;
        hv2 = (ww == 2) ? nv : hv2;  hi2 = (ww == 2) ? ni : hi2;
        hv3 = (ww == 3) ? nv : hv3;  hi3 = (ww == 3) ? ni : hi3;
    }

    // ---- edge diffs for this lane's 5 neighbors (k = 4j + c) ----
    float d0[5], d1[5], d2[5];
    {
        const int mjs[5] = { mi0, mi1, mi2, mi3, mi4 };
        #pragma unroll
        for (int j = 0; j < 5; ++j) {
            const int m = mjs[j];
            d0[j] = xnf - xg[m];
            d1[j] = ynf - xg[NPTS + m];
            d2[j] = znf - xg[2 * NPTS + m];
        }
    }

    // ---- attention logits + edge_feature output ----
    float sacc[5], nacc[5];
    #pragma unroll
    for (int j = 0; j < 5; ++j) { sacc[j] = 0.f; nacc[j] = 0.f; }

    const float fb3 = fb3s;
    for (int o = 0; o < 16; ++o) {
        const float4 wa = wA[o];
        const float4 we = wE[o];
        const float w3o = w3s[o];
        const size_t ebase = (((size_t)b * 16 + o) * NPTS + n) * KNN + c;
        #pragma unroll
        for (int j = 0; j < 5; ++j) {
            float f1 = fmaf(d2[j], wa.z, fmaf(d1[j], wa.y, fmaf(d0[j], wa.x, wa.w)));
            f1 = fmaxf(f1, 0.f);
            sacc[j] = fmaf(f1, w3o, sacc[j]);
            float ee = fmaf(d2[j], we.z, fmaf(d1[j], we.y, fmaf(d0[j], we.x, we.w)));
            ee = fmaxf(ee, 0.f);
            nacc[j] = fmaf(ee, w3o, nacc[j]);
            out_edge[ebase + 4 * j] = ee;
        }
    }

    // ---- leaky_relu + softmax over k (group of 4 lanes = one point) ----
    float att[5];
    float mx = NEGBIG;
    #pragma unroll
    for (int j = 0; j < 5; ++j) {
        float l = fmaxf(sacc[j] + fb3, 0.f) + fmaxf(nacc[j] + fb3, 0.f);
        l = (l >= 0.f) ? l : 0.01f * l;
        att[j] = l;
        mx = fmaxf(mx, l);
    }
    mx = fmaxf(mx, __shfl_xor(mx, 1));
    mx = fmaxf(mx, __shfl_xor(mx, 2));
    float sum = 0.f;
    #pragma unroll
    for (int j = 0; j < 5; ++j) { att[j] = expf(att[j] - mx); sum += att[j]; }
    sum += __shfl_xor(sum, 1);
    sum += __shfl_xor(sum, 2);
    const float inv = 1.f / sum;
    #pragma unroll
    for (int j = 0; j < 5; ++j) att[j] *= inv;

    // ---- weighted edge sum (recompute edge), group-reduce, elu, write ret ----
    float val[16];
    #pragma unroll
    for (int o = 0; o < 16; ++o) val[o] = 0.f;
    for (int o = 0; o < 16; ++o) {
        const float4 we = wE[o];
        float v = 0.f;
        #pragma unroll
        for (int j = 0; j < 5; ++j) {
            float ee = fmaf(d2[j], we.z, fmaf(d1[j], we.y, fmaf(d0[j], we.x, we.w)));
            ee = fmaxf(ee, 0.f);
            v = fmaf(att[j], ee, v);
        }
        val[o] = v;
    }
    #pragma unroll
    for (int o = 0; o < 16; ++o) {
        val[o] += __shfl_xor(val[o], 1);
        val[o] += __shfl_xor(val[o], 2);
    }
    const size_t rbase = ((size_t)b * NPTS + n) * 16;
    #pragma unroll
    for (int oi = 0; oi < 4; ++oi) {
        const int o = 4 * c + oi;
        const float vv = val[o];
        out_ret[rbase + o] = (vv > 0.f) ? vv : expm1f(vv);
    }
}

extern "C" void kernel_launch(void* const* d_in, const int* in_sizes, int n_in,
                              void* d_out, int out_size, void* d_ws, size_t ws_size,
                              hipStream_t stream) {
    (void)d_ws; (void)ws_size; (void)n_in; (void)out_size;
    const float* x   = (const float*)d_in[0];
    const float* w1  = (const float*)d_in[1];
    const float* g1  = (const float*)d_in[2];
    const float* be1 = (const float*)d_in[3];
    const float* mu1 = (const float*)d_in[4];
    const float* va1 = (const float*)d_in[5];
    const float* w2  = (const float*)d_in[6];
    const float* b2  = (const float*)d_in[7];
    const float* g2  = (const float*)d_in[8];
    const float* be2 = (const float*)d_in[9];
    const float* mu2 = (const float*)d_in[10];
    const float* va2 = (const float*)d_in[11];
    const float* w3  = (const float*)d_in[12];
    const float* b3  = (const float*)d_in[13];
    const float* g3  = (const float*)d_in[14];
    const float* be3 = (const float*)d_in[15];
    const float* mu3 = (const float*)d_in[16];
    const float* va3 = (const float*)d_in[17];

    const int B = in_sizes[0] / (3 * NPTS);   // = 8
    float* out_ret  = (float*)d_out;                          // B*N*16
    float* out_edge = out_ret + (size_t)B * NPTS * 16;        // B*16*N*K

    const int grid = B * (NPTS / PPB);        // 8 * 64 = 512 blocks
    gap_layer_kernel<<<grid, BLK, 0, stream>>>(
        x, w1, g1, be1, mu1, va1, w2, b2, g2, be2, mu2, va2,
        w3, b3, g3, be3, mu3, va3, out_ret, out_edge);
}

// Round 10
// 385.938 us; speedup vs baseline: 2.9939x; 1.3868x over previous
//
#include <hip/hip_runtime.h>
#include <math.h>

#define NPTS  4096
#define KNN   20
#define BLK   256
#define SPLIT 4
#define CHUNK (NPTS / SPLIT)   // 1024 candidates per sub-scan
#define PPB   (BLK / SPLIT)    // 64 points per block
#define BUF   4
#define NEGBIG -3.4e38f
#define ROWSTRIDE 21

// ---------- pass 1: stage (x,y,z,xx) as float4 in workspace ----------
__global__ __launch_bounds__(256) void stage_kernel(
    const float* __restrict__ x, float4* __restrict__ ws)
{
    const int i = blockIdx.x * 256 + threadIdx.x;   // over B*NPTS
    const int b = i >> 12;
    const int m = i & (NPTS - 1);
    const float* xb = x + (size_t)b * 3 * NPTS;
    {
        #pragma clang fp contract(off)
        const float a = xb[m];
        const float c = xb[NPTS + m];
        const float e = xb[2 * NPTS + m];
        // frozen np rounding: xx = ((a*a)+(c*c))+(e*e), per-op rounded, NO fma
        const float pa = a * a;
        const float pc = c * c;
        const float pe = e * e;
        const float s01 = pa + pc;
        const float xx = s01 + pe;
        ws[i] = make_float4(a, c, e, xx);
    }
}

// full stable sorted-insert body (strict >; equal keys keep earlier m)
#define INSERT_BODY(VV, II)                                              \
    {                                                                    \
        bool cc_[KNN];                                                   \
        _Pragma("unroll")                                                \
        for (int j_ = 0; j_ < KNN; ++j_) cc_[j_] = (VV) > bv[j_];        \
        _Pragma("unroll")                                                \
        for (int j_ = KNN - 1; j_ >= 1; --j_) {                          \
            bv[j_] = cc_[j_] ? (cc_[j_ - 1] ? bv[j_ - 1] : (VV)) : bv[j_]; \
            bi[j_] = cc_[j_] ? (cc_[j_ - 1] ? bi[j_ - 1] : (II)) : bi[j_]; \
        }                                                                \
        if (cc_[0]) { bv[0] = (VV); bi[0] = (II); }                      \
    }

__global__ __launch_bounds__(BLK, 4) void gap_layer_kernel(
    const float4* __restrict__ xs4,   // staged (x,y,z,xx), B*NPTS
    const float* __restrict__ w1,
    const float* __restrict__ g1, const float* __restrict__ be1,
    const float* __restrict__ mu1, const float* __restrict__ va1,
    const float* __restrict__ w2, const float* __restrict__ b2,
    const float* __restrict__ g2, const float* __restrict__ be2,
    const float* __restrict__ mu2, const float* __restrict__ va2,
    const float* __restrict__ w3, const float* __restrict__ b3,
    const float* __restrict__ g3, const float* __restrict__ be3,
    const float* __restrict__ mu3, const float* __restrict__ va3,
    float* __restrict__ out_ret,   // (B, N, 16) flat
    float* __restrict__ out_edge)  // (B, 16, N, KNN) flat
{
    __shared__ float2 smrg[PPB * SPLIT * ROWSTRIDE];
    __shared__ float4 wA[16], wE[16];
    __shared__ float  w3s[16];
    __shared__ float  fb3s;

    const int tid = threadIdx.x;
    const int p   = tid >> 2;      // local point 0..63
    const int c   = tid & 3;       // chunk id 0..3
    const int b     = blockIdx.x >> 6;
    const int nbase = (blockIdx.x & 63) * PPB;
    const int n     = nbase + p;

    if (tid < 16) {
        const int o = tid;
        float s1 = g1[o] * rsqrtf(va1[o] + 1e-5f);
        float fb1o = -mu1[o] * s1 + be1[o];
        wA[o] = make_float4(w1[o*3+0]*s1, w1[o*3+1]*s1, w1[o*3+2]*s1, fb1o);
        float s2 = g2[o] * rsqrtf(va2[o] + 1e-5f);
        float fb2o = (b2[o] - mu2[o]) * s2 + be2[o];
        wE[o] = make_float4(w2[o*3+0]*s2, w2[o*3+1]*s2, w2[o*3+2]*s2, fb2o);
        float s3 = g3[0] * rsqrtf(va3[0] + 1e-5f);
        w3s[o] = w3[o] * s3;
        if (o == 0) fb3s = (b3[0] - mu3[0]) * s3 + be3[0];
    }

    const float4* xb4 = xs4 + (size_t)b * NPTS;
    const float4 me = xb4[n];
    const float xnf = me.x, ynf = me.y, znf = me.z, xxn = me.w;

    // ---- sub-scan with lane-local candidate buffer ----
    float bv[KNN];
    int   bi[KNN];
    #pragma unroll
    for (int j = 0; j < KNN; ++j) { bv[j] = NEGBIG; bi[j] = 0; }
    float bufv[BUF];
    int   bufi[BUF];
    #pragma unroll
    for (int j = 0; j < BUF; ++j) { bufv[j] = NEGBIG; bufi[j] = 0; }
    int cnt = 0;

    #pragma unroll 4
    for (int t = 0; t < CHUNK; ++t) {
        const int m = (t << 2) | c;
        const float4 q = xb4[m];
        float v;
        {
            #pragma clang fp contract(off)
            const float p0    = xnf * q.x;
            const float f1    = __builtin_fmaf(ynf, q.y, p0);
            const float inner = __builtin_fmaf(znf, q.z, f1);
            const float two_i = inner + inner;
            const float tt    = two_i - q.w;
            v = tt - xxn;
        }
        const bool pass = v > bv[KNN - 1];
        #pragma unroll
        for (int j = 0; j < BUF; ++j) {
            const bool s = pass && (cnt == j);
            bufv[j] = s ? v : bufv[j];
            bufi[j] = s ? m : bufi[j];
        }
        cnt += pass ? 1 : 0;
        if (__any(cnt == BUF)) {
            #pragma unroll
            for (int j = 0; j < BUF; ++j) {
                INSERT_BODY(bufv[j], bufi[j]);
                bufv[j] = NEGBIG;
            }
            cnt = 0;
        }
    }
    // final drain
    #pragma unroll
    for (int j = 0; j < BUF; ++j) INSERT_BODY(bufv[j], bufi[j]);

    // ---- publish sorted sub-lists to LDS ----
    {
        float2* row = &smrg[tid * ROWSTRIDE];
        #pragma unroll
        for (int j = 0; j < KNN; ++j)
            row[j] = make_float2(bv[j], __int_as_float(bi[j]));
    }
    __syncthreads();

    // ---- 4-way merge (comparator: v desc, idx asc); lane c keeps r%4==c ----
    const float2* base = &smrg[(p << 2) * ROWSTRIDE];
    float2 h;
    h = base[0];                 float hv0 = h.x; int hi0 = __float_as_int(h.y);
    h = base[ROWSTRIDE];         float hv1 = h.x; int hi1 = __float_as_int(h.y);
    h = base[2 * ROWSTRIDE];     float hv2 = h.x; int hi2 = __float_as_int(h.y);
    h = base[3 * ROWSTRIDE];     float hv3 = h.x; int hi3 = __float_as_int(h.y);
    int q0 = 1, q1 = 1, q2 = 1, q3 = 1;
    int mi0 = 0, mi1 = 0, mi2 = 0, mi3 = 0, mi4 = 0;

    #pragma unroll
    for (int r = 0; r < KNN; ++r) {
        const bool b01 = (hv1 > hv0) || (hv1 == hv0 && hi1 < hi0);
        const float av = b01 ? hv1 : hv0;
        const int   ai = b01 ? hi1 : hi0;
        const int   aw = b01 ? 1 : 0;
        const bool b23 = (hv3 > hv2) || (hv3 == hv2 && hi3 < hi2);
        const float bvv = b23 ? hv3 : hv2;
        const int   bii = b23 ? hi3 : hi2;
        const int   bw  = b23 ? 3 : 2;
        const bool bab = (bvv > av) || (bvv == av && bii < ai);
        const int wi = bab ? bii : ai;
        const int ww = bab ? bw : aw;

        if ((r & 3) == c) {
            const int j = r >> 2;
            mi0 = (j == 0) ? wi : mi0;
            mi1 = (j == 1) ? wi : mi1;
            mi2 = (j == 2) ? wi : mi2;
            mi3 = (j == 3) ? wi : mi3;
            mi4 = (j == 4) ? wi : mi4;
        }

        const int qw = (ww == 0) ? q0 : (ww == 1) ? q1 : (ww == 2) ? q2 : q3;
        const int rd = (qw < KNN - 1) ? qw : (KNN - 1);
        const float2 nh = base[ww * ROWSTRIDE + rd];
        const float nv = (qw < KNN) ? nh.x : NEGBIG;
        const int   ni = __float_as_int(nh.y);
        q0 += (ww == 0); q1 += (ww == 1); q2 += (ww == 2); q3 += (ww == 3);
        hv0 = (ww == 0) ? nv : hv0;  hi0 = (ww == 0) ? ni : hi0;
        hv1 = (ww == 1) ? nv : hv1;  hi1 = (ww == 1) ? ni : hi1;
        hv2 = (ww == 2) ? nv : hv2;  hi2 = (ww == 2) ? ni : hi2;
        hv3 = (ww == 3) ? nv : hv3;  hi3 = (ww == 3) ? ni : hi3;
    }

    // ---- edge diffs for this lane's 5 neighbors (k = 4j + c) ----
    float d0[5], d1[5], d2[5];
    {
        const int mjs[5] = { mi0, mi1, mi2, mi3, mi4 };
        #pragma unroll
        for (int j = 0; j < 5; ++j) {
            const float4 q = xb4[mjs[j]];
            d0[j] = xnf - q.x;
            d1[j] = ynf - q.y;
            d2[j] = znf - q.z;
        }
    }

    // ---- attention logits + edge_feature output ----
    float sacc[5], nacc[5];
    #pragma unroll
    for (int j = 0; j < 5; ++j) { sacc[j] = 0.f; nacc[j] = 0.f; }

    const float fb3 = fb3s;
    for (int o = 0; o < 16; ++o) {
        const float4 wa = wA[o];
        const float4 we = wE[o];
        const float w3o = w3s[o];
        const size_t ebase = (((size_t)b * 16 + o) * NPTS + n) * KNN + c;
        #pragma unroll
        for (int j = 0; j < 5; ++j) {
            float f1 = fmaf(d2[j], wa.z, fmaf(d1[j], wa.y, fmaf(d0[j], wa.x, wa.w)));
            f1 = fmaxf(f1, 0.f);
            sacc[j] = fmaf(f1, w3o, sacc[j]);
            float ee = fmaf(d2[j], we.z, fmaf(d1[j], we.y, fmaf(d0[j], we.x, we.w)));
            ee = fmaxf(ee, 0.f);
            nacc[j] = fmaf(ee, w3o, nacc[j]);
            out_edge[ebase + 4 * j] = ee;
        }
    }

    // ---- leaky_relu + softmax over k (group of 4 lanes = one point) ----
    float att[5];
    float mx = NEGBIG;
    #pragma unroll
    for (int j = 0; j < 5; ++j) {
        float l = fmaxf(sacc[j] + fb3, 0.f) + fmaxf(nacc[j] + fb3, 0.f);
        l = (l >= 0.f) ? l : 0.01f * l;
        att[j] = l;
        mx = fmaxf(mx, l);
    }
    mx = fmaxf(mx, __shfl_xor(mx, 1));
    mx = fmaxf(mx, __shfl_xor(mx, 2));
    float sum = 0.f;
    #pragma unroll
    for (int j = 0; j < 5; ++j) { att[j] = expf(att[j] - mx); sum += att[j]; }
    sum += __shfl_xor(sum, 1);
    sum += __shfl_xor(sum, 2);
    const float inv = 1.f / sum;
    #pragma unroll
    for (int j = 0; j < 5; ++j) att[j] *= inv;

    // ---- weighted edge sum (recompute edge), group-reduce, elu, write ret ----
    float val[16];
    for (int o = 0; o < 16; ++o) {
        const float4 we = wE[o];
        float v = 0.f;
        #pragma unroll
        for (int j = 0; j < 5; ++j) {
            float ee = fmaf(d2[j], we.z, fmaf(d1[j], we.y, fmaf(d0[j], we.x, we.w)));
            ee = fmaxf(ee, 0.f);
            v = fmaf(att[j], ee, v);
        }
        val[o] = v;
    }
    #pragma unroll
    for (int o = 0; o < 16; ++o) {
        val[o] += __shfl_xor(val[o], 1);
        val[o] += __shfl_xor(val[o], 2);
    }
    const size_t rbase = ((size_t)b * NPTS + n) * 16;
    #pragma unroll
    for (int oi = 0; oi < 4; ++oi) {
        const int o = 4 * c + oi;
        const float vv = val[o];
        out_ret[rbase + o] = (vv > 0.f) ? vv : expm1f(vv);
    }
}

extern "C" void kernel_launch(void* const* d_in, const int* in_sizes, int n_in,
                              void* d_out, int out_size, void* d_ws, size_t ws_size,
                              hipStream_t stream) {
    (void)n_in; (void)out_size; (void)ws_size;
    const float* x   = (const float*)d_in[0];
    const float* w1  = (const float*)d_in[1];
    const float* g1  = (const float*)d_in[2];
    const float* be1 = (const float*)d_in[3];
    const float* mu1 = (const float*)d_in[4];
    const float* va1 = (const float*)d_in[5];
    const float* w2  = (const float*)d_in[6];
    const float* b2  = (const float*)d_in[7];
    const float* g2  = (const float*)d_in[8];
    const float* be2 = (const float*)d_in[9];
    const float* mu2 = (const float*)d_in[10];
    const float* va2 = (const float*)d_in[11];
    const float* w3  = (const float*)d_in[12];
    const float* b3  = (const float*)d_in[13];
    const float* g3  = (const float*)d_in[14];
    const float* be3 = (const float*)d_in[15];
    const float* mu3 = (const float*)d_in[16];
    const float* va3 = (const float*)d_in[17];

    const int B = in_sizes[0] / (3 * NPTS);   // = 8
    float* out_ret  = (float*)d_out;                          // B*N*16
    float* out_edge = out_ret + (size_t)B * NPTS * 16;        // B*16*N*K

    float4* xs4 = (float4*)d_ws;              // B*NPTS float4 = 512 KB

    stage_kernel<<<B * NPTS / 256, 256, 0, stream>>>(x, xs4);

    const int grid = B * (NPTS / PPB);        // 512 blocks
    gap_layer_kernel<<<grid, BLK, 0, stream>>>(
        xs4, w1, g1, be1, mu1, va1, w2, b2, g2, be2, mu2, va2,
        w3, b3, g3, be3, mu3, va3, out_ret, out_edge);
}